// Round 9
// baseline (2391.656 us; speedup 1.0000x reference)
//
#include <hip/hip_runtime.h>

// LSTM predictor: B=2048 rows, T=2048 + 128 future, H=51.
// ONE WAVE per batch row (grid 2048 x 64), barrier-free.
// Round 7/8 post-mortem: inline-asm v_dot2 encoding is a dead end (default
// modifier state mis-computes; explicit op_sel_hi rejected by the parser).
// Round-6 issue arithmetic (345 inst/wave-step = 104*3 + overhead) says
// __builtin_amdgcn_fdot2 expands to ~3 VALU inst. This round replaces each
// dot2 with two SOURCE-LEVEL mixed FMAs: fmaf((float)w16, (float)h16, acc)
// -> single v_fma_mix_f32 (native gfx9+ ISel pattern, op_sel picks halves,
// product in full fp32). Nominal matvec: 204 fma_mix vs ~312 effective now.
// W_hh stays packed f16 (104 VGPRs - the register-pressure win). h published
// to LDS as f16, read via 7 uniform-address ds_read_b128 broadcasts.
// Biases, x path, c, fc head stay fp32.

typedef _Float16 v2h __attribute__((ext_vector_type(2)));
typedef float    v4f __attribute__((ext_vector_type(4)));

constexpr int Hh = 51;

__device__ __forceinline__ float fexp2(float x){ return __builtin_amdgcn_exp2f(x); }
__device__ __forceinline__ float frcp(float x) { return __builtin_amdgcn_rcpf(x); }
// sigmoid(x) = 1/(1+2^(-x*log2e))
__device__ __forceinline__ float sigm(float x) { return frcp(1.f + fexp2(-1.44269504f * x)); }
// tanh(x) = 1 - 2/(1+2^(2x*log2e))
__device__ __forceinline__ float tanh_f(float x){ return 1.f - 2.f * frcp(1.f + fexp2(2.88539008f * x)); }

__device__ __forceinline__ float rdlane(float v, int lane){
  return __int_as_float(__builtin_amdgcn_readlane(__float_as_int(v), lane));
}

__device__ __forceinline__ v2h bch(float f){
  union { float f; v2h h; } u; u.f = f; return u.h;
}

// Two mixed-precision MACs: acc += w.x*h.x + w.y*h.y, products in fp32.
// Each fmaf((float)f16, (float)f16, f32) folds to one v_fma_mix_f32.
__device__ __forceinline__ float mac2(v2h w, v2h h, float acc){
  acc = fmaf((float)w.x, (float)h.x, acc);
  acc = fmaf((float)w.y, (float)h.y, acc);
  return acc;
}

__global__ __launch_bounds__(64)
__attribute__((amdgpu_waves_per_eu(1)))
void lstm_kernel(const float* __restrict__ x,
                 const float* __restrict__ W_ih,
                 const float* __restrict__ W_hh,
                 const float* __restrict__ b_ih,
                 const float* __restrict__ b_hh,
                 const float* __restrict__ fc_w,
                 const float* __restrict__ fc_b,
                 float* __restrict__ out,
                 int T, int OT)
{
  const int k   = threadIdx.x;   // lane = hidden unit
  const int row = blockIdx.x;    // batch row

  __shared__ __align__(16) _Float16 hbuf16[64];  // h as f16; [52..63] junk, never read
  __shared__ float st[64][65];                   // fc stash: st[lane][step_in_chunk]

  hbuf16[k] = (_Float16)0.f;

  // ---- weights: 4 gate rows per lane as f16 pairs (pair 25: {w[50], 0})
  const int kc = (k < Hh) ? k : (Hh - 1);        // clamp, no divergence
  v2h w0[26], w1[26], w2[26], w3[26];
  const long r0 = (long)(0 * Hh + kc) * Hh;
  const long r1 = (long)(1 * Hh + kc) * Hh;
  const long r2 = (long)(2 * Hh + kc) * Hh;
  const long r3 = (long)(3 * Hh + kc) * Hh;
#pragma unroll
  for (int m = 0; m < 25; ++m) {
    w0[m] = (v2h){(_Float16)W_hh[r0 + 2*m], (_Float16)W_hh[r0 + 2*m + 1]};
    w1[m] = (v2h){(_Float16)W_hh[r1 + 2*m], (_Float16)W_hh[r1 + 2*m + 1]};
    w2[m] = (v2h){(_Float16)W_hh[r2 + 2*m], (_Float16)W_hh[r2 + 2*m + 1]};
    w3[m] = (v2h){(_Float16)W_hh[r3 + 2*m], (_Float16)W_hh[r3 + 2*m + 1]};
  }
  w0[25] = (v2h){(_Float16)W_hh[r0 + 50], (_Float16)0.f};
  w1[25] = (v2h){(_Float16)W_hh[r1 + 50], (_Float16)0.f};
  w2[25] = (v2h){(_Float16)W_hh[r2 + 50], (_Float16)0.f};
  w3[25] = (v2h){(_Float16)W_hh[r3 + 50], (_Float16)0.f};
  const float wi0 = W_ih[0 * Hh + kc], wi1 = W_ih[1 * Hh + kc];
  const float wi2 = W_ih[2 * Hh + kc], wi3 = W_ih[3 * Hh + kc];
  const float bs0 = b_ih[0 * Hh + kc] + b_hh[0 * Hh + kc];
  const float bs1 = b_ih[1 * Hh + kc] + b_hh[1 * Hh + kc];
  const float bs2 = b_ih[2 * Hh + kc] + b_hh[2 * Hh + kc];
  const float bs3 = b_ih[3 * Hh + kc] + b_hh[3 * Hh + kc];
  const float fcw = (k < Hh) ? fc_w[k] : 0.f;
  const float fcb = fc_b[0];

  float c = 0.f, h = 0.f;

  auto cell = [&](float xt) {
    float a0 = fmaf(xt, wi0, bs0);
    float a1 = fmaf(xt, wi1, bs1);
    float a2 = fmaf(xt, wi2, bs2);
    float a3 = fmaf(xt, wi3, bs3);
    const v4f* hb4 = (const v4f*)hbuf16;   // 8 halfs per read, word = f16 pair
#pragma unroll
    for (int q = 0; q < 7; ++q) {
      const v4f hv = hb4[q];               // uniform-address broadcast read
      const int p = 4 * q;                 // first h-pair index in this word
      const v2h h0 = bch(hv.x), h1 = bch(hv.y), h2 = bch(hv.z), h3 = bch(hv.w);
      a0 = mac2(w0[p], h0, a0);
      a1 = mac2(w1[p], h0, a1);
      a2 = mac2(w2[p], h0, a2);
      a3 = mac2(w3[p], h0, a3);
      if (p + 1 < 26) {
        a0 = mac2(w0[p+1], h1, a0); a1 = mac2(w1[p+1], h1, a1);
        a2 = mac2(w2[p+1], h1, a2); a3 = mac2(w3[p+1], h1, a3);
      }
      if (p + 2 < 26) {
        a0 = mac2(w0[p+2], h2, a0); a1 = mac2(w1[p+2], h2, a1);
        a2 = mac2(w2[p+2], h2, a2); a3 = mac2(w3[p+2], h2, a3);
      }
      if (p + 3 < 26) {
        a0 = mac2(w0[p+3], h3, a0); a1 = mac2(w1[p+3], h3, a1);
        a2 = mac2(w2[p+3], h3, a2); a3 = mac2(w3[p+3], h3, a3);
      }
    }
    const float ia = sigm(a0);
    const float fa = sigm(a1);
    const float ga = tanh_f(a2);
    const float oa = sigm(a3);
    c = fmaf(fa, c, ia * ga);
    h = oa * tanh_f(c);
    asm volatile("" ::: "memory");
    hbuf16[k] = (_Float16)h;               // publish for next step (same-wave FIFO)
    asm volatile("" ::: "memory");
  };

  // ---- main phase: T steps in chunks of 64
  float s = fcb;
  for (int tc = 0; tc < T; tc += 64) {
    const float xv = x[(long)row * T + tc + k];   // coalesced chunk load
#pragma unroll 1
    for (int i = 0; i < 64; ++i) {
      cell(rdlane(xv, i));
      st[k][i] = h * fcw;                  // conflict-free (stride 65)
    }
    // transpose-reduce: lane t sums column t -> out[tc + t]
    s = fcb;
#pragma unroll
    for (int j = 0; j < 64; ++j) s += st[j][k];   // conflict-free per j
    asm volatile("" ::: "memory");
    out[(long)row * OT + tc + k] = s;      // coalesced store
  }

  // ---- future phase: feedback out -> x, butterfly reduce each step
  float out_prev = rdlane(s, 63);          // out[T-1]
  float obuf = 0.f;
  for (int t = T; t < OT; ++t) {
    cell(out_prev);
    float p = h * fcw;
#pragma unroll
    for (int off = 32; off > 0; off >>= 1) p += __shfl_xor(p, off, 64);
    const float out_t = p + fcb;
    obuf = (k == (t & 63)) ? out_t : obuf;
    if ((t & 63) == 63)
      out[(long)row * OT + (t - 63) + k] = obuf;  // coalesced
    out_prev = out_t;
  }
}

extern "C" void kernel_launch(void* const* d_in, const int* in_sizes, int n_in,
                              void* d_out, int out_size, void* d_ws, size_t ws_size,
                              hipStream_t stream) {
  const float* x    = (const float*)d_in[0];
  const float* W_ih = (const float*)d_in[1];
  const float* W_hh = (const float*)d_in[2];
  const float* b_ih = (const float*)d_in[3];
  const float* b_hh = (const float*)d_in[4];
  const float* fc_w = (const float*)d_in[5];
  const float* fc_b = (const float*)d_in[6];
  float* out = (float*)d_out;

  const int B  = 2048;
  const int T  = in_sizes[0] / B;   // 2048
  const int OT = out_size / B;      // 2176

  lstm_kernel<<<dim3(B), dim3(64), 0, stream>>>(x, W_ih, W_hh, b_ih, b_hh,
                                                fc_w, fc_b, out, T, OT);
}

// Round 11
// 1600.747 us; speedup vs baseline: 1.4941x; 1.4941x over previous
//
#include <hip/hip_runtime.h>

// LSTM predictor: B=2048 rows, T=2048 + 128 future, H=51.
// ONE WAVE per batch row (grid 2048 x 64), barrier-free.
// Lineage: r6 = f16 weight pairs (104 VGPRs) + __builtin_amdgcn_fdot2 = 1299us.
// r10 = register h-broadcast via DPP, FAILED on DPP direction: row_shr:1
// (0x111) delivers lane i-1's value (canonical DPP scan idiom), so pairs
// were (h_2m, h_{2m-1}). THIS ROUND: single fix 0x111 -> 0x101 (row_shl:1 =
// lane i+1's value) giving pairs (h_2m, h_{2m+1}). Even-lane pairs never
// cross a 16-lane DPP row boundary, so bound_ctrl zeroing is never consumed.
// h broadcast: cvt h to f16, DPP fetch neighbor half, pack 32-bit pair,
// 26 compile-time v_readlane -> SGPR feeds fdot2's legal scalar operand.
// No LDS in the recurrence (st[] is only the per-64-step fc stash).

typedef _Float16 v2h __attribute__((ext_vector_type(2)));

constexpr int Hh = 51;

__device__ __forceinline__ float fexp2(float x){ return __builtin_amdgcn_exp2f(x); }
__device__ __forceinline__ float frcp(float x) { return __builtin_amdgcn_rcpf(x); }
// sigmoid(x) = 1/(1+2^(-x*log2e))
__device__ __forceinline__ float sigm(float x) { return frcp(1.f + fexp2(-1.44269504f * x)); }
// tanh(x) = 1 - 2/(1+2^(2x*log2e))
__device__ __forceinline__ float tanh_f(float x){ return 1.f - 2.f * frcp(1.f + fexp2(2.88539008f * x)); }

__device__ __forceinline__ float rdlane(float v, int lane){
  return __int_as_float(__builtin_amdgcn_readlane(__float_as_int(v), lane));
}

__device__ __forceinline__ float dot2(v2h a, v2h b, float c){
  return __builtin_amdgcn_fdot2(a, b, c, false);
}

__global__ __launch_bounds__(64)
__attribute__((amdgpu_waves_per_eu(1)))
void lstm_kernel(const float* __restrict__ x,
                 const float* __restrict__ W_ih,
                 const float* __restrict__ W_hh,
                 const float* __restrict__ b_ih,
                 const float* __restrict__ b_hh,
                 const float* __restrict__ fc_w,
                 const float* __restrict__ fc_b,
                 float* __restrict__ out,
                 int T, int OT)
{
  const int k   = threadIdx.x;   // lane = hidden unit
  const int row = blockIdx.x;    // batch row

  __shared__ float st[64][65];   // fc stash: st[lane][step_in_chunk]

  // ---- weights: 4 gate rows per lane as f16 pairs (pair 25: {w[50], 0})
  const int kc = (k < Hh) ? k : (Hh - 1);        // clamp, no divergence
  v2h w0[26], w1[26], w2[26], w3[26];
  const long r0 = (long)(0 * Hh + kc) * Hh;
  const long r1 = (long)(1 * Hh + kc) * Hh;
  const long r2 = (long)(2 * Hh + kc) * Hh;
  const long r3 = (long)(3 * Hh + kc) * Hh;
#pragma unroll
  for (int m = 0; m < 25; ++m) {
    w0[m] = (v2h){(_Float16)W_hh[r0 + 2*m], (_Float16)W_hh[r0 + 2*m + 1]};
    w1[m] = (v2h){(_Float16)W_hh[r1 + 2*m], (_Float16)W_hh[r1 + 2*m + 1]};
    w2[m] = (v2h){(_Float16)W_hh[r2 + 2*m], (_Float16)W_hh[r2 + 2*m + 1]};
    w3[m] = (v2h){(_Float16)W_hh[r3 + 2*m], (_Float16)W_hh[r3 + 2*m + 1]};
  }
  w0[25] = (v2h){(_Float16)W_hh[r0 + 50], (_Float16)0.f};
  w1[25] = (v2h){(_Float16)W_hh[r1 + 50], (_Float16)0.f};
  w2[25] = (v2h){(_Float16)W_hh[r2 + 50], (_Float16)0.f};
  w3[25] = (v2h){(_Float16)W_hh[r3 + 50], (_Float16)0.f};
  const float wi0 = W_ih[0 * Hh + kc], wi1 = W_ih[1 * Hh + kc];
  const float wi2 = W_ih[2 * Hh + kc], wi3 = W_ih[3 * Hh + kc];
  const float bs0 = b_ih[0 * Hh + kc] + b_hh[0 * Hh + kc];
  const float bs1 = b_ih[1 * Hh + kc] + b_hh[1 * Hh + kc];
  const float bs2 = b_ih[2 * Hh + kc] + b_hh[2 * Hh + kc];
  const float bs3 = b_ih[3 * Hh + kc] + b_hh[3 * Hh + kc];
  const float fcw = (k < Hh) ? fc_w[k] : 0.f;
  const float fcb = fc_b[0];

  float c = 0.f, h = 0.f;
  int   pairv = 0;               // packed (h16_k, h16_{k+1}) for this lane; h=0 init

  auto cell = [&](float xt) {
    float a0 = fmaf(xt, wi0, bs0);
    float a1 = fmaf(xt, wi1, bs1);
    float a2 = fmaf(xt, wi2, bs2);
    float a3 = fmaf(xt, wi3, bs3);
#pragma unroll
    for (int m = 0; m < 26; ++m) {
      // lane 2m holds pair (h_2m, h_2m+1); readlane -> SGPR, legal dot2 src
      const v2h hp = __builtin_bit_cast(v2h, __builtin_amdgcn_readlane(pairv, 2*m));
      a0 = dot2(w0[m], hp, a0);
      a1 = dot2(w1[m], hp, a1);
      a2 = dot2(w2[m], hp, a2);
      a3 = dot2(w3[m], hp, a3);
    }
    const float ia = sigm(a0);
    const float fa = sigm(a1);
    const float ga = tanh_f(a2);
    const float oa = sigm(a3);
    c = fmaf(fa, c, ia * ga);
    h = oa * tanh_f(c);

    // ---- register broadcast prep: pair = (h16_k | h16_{k+1} << 16)
    const float hz = (k < Hh) ? h : 0.f;             // lanes >= 51 contribute 0
    const unsigned hl =
        (unsigned)__builtin_bit_cast(unsigned short, (_Float16)hz);
    const unsigned hn =
        (unsigned)__builtin_amdgcn_mov_dpp((int)hl, 0x101, 0xF, 0xF, true);
    pairv = (int)(hl | (hn << 16));                  // row_shl:1 -> lane k+1's h
  };

  // ---- main phase: T steps in chunks of 64
  float s = fcb;
  for (int tc = 0; tc < T; tc += 64) {
    const float xv = x[(long)row * T + tc + k];   // coalesced chunk load
#pragma unroll 1
    for (int i = 0; i < 64; ++i) {
      cell(rdlane(xv, i));
      st[k][i] = h * fcw;                  // conflict-free (stride 65)
    }
    // transpose-reduce: lane t sums column t -> out[tc + t]
    s = fcb;
#pragma unroll
    for (int j = 0; j < 64; ++j) s += st[j][k];   // conflict-free per j
    asm volatile("" ::: "memory");
    out[(long)row * OT + tc + k] = s;      // coalesced store
  }

  // ---- future phase: feedback out -> x, butterfly reduce each step
  float out_prev = rdlane(s, 63);          // out[T-1]
  float obuf = 0.f;
  for (int t = T; t < OT; ++t) {
    cell(out_prev);
    float p = h * fcw;
#pragma unroll
    for (int off = 32; off > 0; off >>= 1) p += __shfl_xor(p, off, 64);
    const float out_t = p + fcb;
    obuf = (k == (t & 63)) ? out_t : obuf;
    if ((t & 63) == 63)
      out[(long)row * OT + (t - 63) + k] = obuf;  // coalesced
    out_prev = out_t;
  }
}

extern "C" void kernel_launch(void* const* d_in, const int* in_sizes, int n_in,
                              void* d_out, int out_size, void* d_ws, size_t ws_size,
                              hipStream_t stream) {
  const float* x    = (const float*)d_in[0];
  const float* W_ih = (const float*)d_in[1];
  const float* W_hh = (const float*)d_in[2];
  const float* b_ih = (const float*)d_in[3];
  const float* b_hh = (const float*)d_in[4];
  const float* fc_w = (const float*)d_in[5];
  const float* fc_b = (const float*)d_in[6];
  float* out = (float*)d_out;

  const int B  = 2048;
  const int T  = in_sizes[0] / B;   // 2048
  const int OT = out_size / B;      // 2176

  lstm_kernel<<<dim3(B), dim3(64), 0, stream>>>(x, W_ih, W_hh, b_ih, b_hh,
                                                fc_w, fc_b, out, T, OT);
}

// Round 12
// 1323.261 us; speedup vs baseline: 1.8074x; 1.2097x over previous
//
#include <hip/hip_runtime.h>

// LSTM predictor: B=2048 rows, T=2048 + 128 future, H=51.
// ONE WAVE per batch row (grid 2048 x 64), barrier-free. Champion r6 base
// (f16 weight pairs in VGPRs + native fdot2, h broadcast via uniform
// ds_read_b128) with three instruction-count trims:
//  1) x folded into dot pair 25: (w50*s, wi*s) . (h50, x16); x injected by
//     overriding the hi-half of LDS word 6 in-register. Dots start at C=bias
//     (kills 4 preact-init FMAs).
//  2) gate weights/biases pre-scaled by log2e: sigm = rcp(1+exp2(-a')) and
//     tanh = 1-2*rcp(1+exp2(a'+a')) lose their input multiplies.
//  3) fc head rides the dots on (otherwise idle) lane 52: its w0 = fc_w,
//     bs0 = fc_b, so lane52.a0 == out(t-1). Kills the st[] stash, the
//     chunk transpose-reduce, and all fc LDS. Emit = readlane + cndmask.
// Future phase (128 steps) keeps the butterfly (out(t) needed same-step).

typedef _Float16 v2h __attribute__((ext_vector_type(2)));
typedef float    v4f __attribute__((ext_vector_type(4)));

constexpr int Hh = 51;

__device__ __forceinline__ float fexp2(float x){ return __builtin_amdgcn_exp2f(x); }
__device__ __forceinline__ float frcp(float x) { return __builtin_amdgcn_rcpf(x); }
// inputs pre-scaled by log2e: sigm(a) with a' = a*log2e
__device__ __forceinline__ float sigm_p(float a){ return frcp(1.f + fexp2(-a)); }
__device__ __forceinline__ float tanh_p(float a){ return 1.f - 2.f * frcp(1.f + fexp2(a + a)); }
// raw-input tanh (for c)
__device__ __forceinline__ float tanh_c(float x){ return 1.f - 2.f * frcp(1.f + fexp2(2.88539008f * x)); }

__device__ __forceinline__ float rdlane(float v, int lane){
  return __int_as_float(__builtin_amdgcn_readlane(__float_as_int(v), lane));
}

__device__ __forceinline__ v2h bch(float f){
  union { float f; v2h h; } u; u.f = f; return u.h;
}
__device__ __forceinline__ v2h ovr_hi(float f, unsigned hi16){
  unsigned u = (__float_as_uint(f) & 0xFFFFu) | (hi16 << 16);
  union { unsigned u; v2h h; } c; c.u = u; return c.h;
}

__device__ __forceinline__ float dot2(v2h a, v2h b, float c){
  return __builtin_amdgcn_fdot2(a, b, c, false);
}

__global__ __launch_bounds__(64)
__attribute__((amdgpu_waves_per_eu(1)))
void lstm_kernel(const float* __restrict__ x,
                 const float* __restrict__ W_ih,
                 const float* __restrict__ W_hh,
                 const float* __restrict__ b_ih,
                 const float* __restrict__ b_hh,
                 const float* __restrict__ fc_w,
                 const float* __restrict__ fc_b,
                 float* __restrict__ out,
                 int T, int OT)
{
  const int k   = threadIdx.x;   // lane = hidden unit (52 = fc lane)
  const int row = blockIdx.x;    // batch row
  const float S = 1.44269504089f;  // log2(e)

  __shared__ __align__(16) _Float16 hbuf16[64];  // h; slot 51+ junk (x overridden in-reg)

  hbuf16[k] = (_Float16)0.f;

  // ---- weights: 4 gate rows per lane as f16 pairs, pre-scaled by log2e.
  // pair 25 = (w50*s, wi*s) -- x folded into the dot stream.
  const int kc = (k < Hh) ? k : (Hh - 1);        // clamp, no divergence
  v2h w0[26], w1[26], w2[26], w3[26];
  const long r0 = (long)(0 * Hh + kc) * Hh;
  const long r1 = (long)(1 * Hh + kc) * Hh;
  const long r2 = (long)(2 * Hh + kc) * Hh;
  const long r3 = (long)(3 * Hh + kc) * Hh;
#pragma unroll
  for (int m = 0; m < 25; ++m) {
    w0[m] = (v2h){(_Float16)(S*W_hh[r0 + 2*m]), (_Float16)(S*W_hh[r0 + 2*m + 1])};
    w1[m] = (v2h){(_Float16)(S*W_hh[r1 + 2*m]), (_Float16)(S*W_hh[r1 + 2*m + 1])};
    w2[m] = (v2h){(_Float16)(S*W_hh[r2 + 2*m]), (_Float16)(S*W_hh[r2 + 2*m + 1])};
    w3[m] = (v2h){(_Float16)(S*W_hh[r3 + 2*m]), (_Float16)(S*W_hh[r3 + 2*m + 1])};
  }
  w0[25] = (v2h){(_Float16)(S*W_hh[r0 + 50]), (_Float16)(S*W_ih[0*Hh + kc])};
  w1[25] = (v2h){(_Float16)(S*W_hh[r1 + 50]), (_Float16)(S*W_ih[1*Hh + kc])};
  w2[25] = (v2h){(_Float16)(S*W_hh[r2 + 50]), (_Float16)(S*W_ih[2*Hh + kc])};
  w3[25] = (v2h){(_Float16)(S*W_hh[r3 + 50]), (_Float16)(S*W_ih[3*Hh + kc])};
  float bs0 = S*(b_ih[0*Hh + kc] + b_hh[0*Hh + kc]);
  const float bs1 = S*(b_ih[1*Hh + kc] + b_hh[1*Hh + kc]);
  const float bs2 = S*(b_ih[2*Hh + kc] + b_hh[2*Hh + kc]);
  const float bs3 = S*(b_ih[3*Hh + kc] + b_hh[3*Hh + kc]);
  const float fcw = (k < Hh) ? fc_w[k] : 0.f;    // f32 head weights (future butterfly)
  const float fcb = fc_b[0];

  if (k == 52) {                                 // fc lane: a0 accumulates out(t-1)
#pragma unroll
    for (int m = 0; m < 25; ++m)
      w0[m] = (v2h){(_Float16)fc_w[2*m], (_Float16)fc_w[2*m + 1]};
    w0[25] = (v2h){(_Float16)fc_w[50], (_Float16)0.f};
    bs0 = fcb;
  }

  float c = 0.f, h = 0.f;

  // cell: one LSTM step; xu16 = f16 bits of x_t. Returns post-dot a0
  // (lane 52's value = out(t-1)).
  auto cell = [&](unsigned xu16) -> float {
    float a0 = bs0, a1 = bs1, a2 = bs2, a3 = bs3;
    const v4f* hb4 = (const v4f*)hbuf16;
#pragma unroll
    for (int q = 0; q < 7; ++q) {
      const v4f hv = hb4[q];               // uniform-address broadcast read
      const int p = 4 * q;                 // first h-pair index in this word
      const v2h h0 = bch(hv.x);
      const v2h h1 = (q == 6) ? ovr_hi(hv.y, xu16) : bch(hv.y);  // x-inject
      const v2h h2 = bch(hv.z), h3 = bch(hv.w);
      a0 = dot2(w0[p], h0, a0);
      a1 = dot2(w1[p], h0, a1);
      a2 = dot2(w2[p], h0, a2);
      a3 = dot2(w3[p], h0, a3);
      if (p + 1 < 26) {
        a0 = dot2(w0[p+1], h1, a0); a1 = dot2(w1[p+1], h1, a1);
        a2 = dot2(w2[p+1], h1, a2); a3 = dot2(w3[p+1], h1, a3);
      }
      if (p + 2 < 26) {
        a0 = dot2(w0[p+2], h2, a0); a1 = dot2(w1[p+2], h2, a1);
        a2 = dot2(w2[p+2], h2, a2); a3 = dot2(w3[p+2], h2, a3);
      }
      if (p + 3 < 26) {
        a0 = dot2(w0[p+3], h3, a0); a1 = dot2(w1[p+3], h3, a1);
        a2 = dot2(w2[p+3], h3, a2); a3 = dot2(w3[p+3], h3, a3);
      }
    }
    const float ia = sigm_p(a0);
    const float fa = sigm_p(a1);
    const float ga = tanh_p(a2);
    const float oa = sigm_p(a3);
    c = fmaf(fa, c, ia * ga);
    h = oa * tanh_c(c);
    asm volatile("" ::: "memory");
    hbuf16[k] = (_Float16)h;               // publish for next step (same-wave FIFO)
    asm volatile("" ::: "memory");
    return a0;
  };

  float obuf = 0.f;

  // ---- main phase: T steps in chunks of 64; fc output emitted one step late
  for (int tc = 0; tc < T; tc += 64) {
    const float xv = x[(long)row * T + tc + k];            // coalesced chunk load
    const unsigned xhu =
        (unsigned)__builtin_bit_cast(unsigned short, (_Float16)xv);
#pragma unroll 1
    for (int i = 0; i < 64; ++i) {
      const int t = tc + i;
      const unsigned xu = (unsigned)__builtin_amdgcn_readlane((int)xhu, i);
      const float a0v = cell(xu);
      const float o = rdlane(a0v, 52);                     // out(t-1)
      if (t > 0) {
        obuf = (k == ((t - 1) & 63)) ? o : obuf;
        if (((t - 1) & 63) == 63)                          // chunk complete
          out[(long)row * OT + (t - 64) + k] = obuf;       // coalesced
      }
    }
  }

  // ---- emit out(T-1) (needs h(T-1), not yet through the dots)
  float p = h * fcw;
#pragma unroll
  for (int off = 32; off > 0; off >>= 1) p += __shfl_xor(p, off, 64);
  float out_prev = p + fcb;
  obuf = (k == 63) ? out_prev : obuf;
  out[(long)row * OT + (T - 64) + k] = obuf;               // last main chunk

  // ---- future phase: feedback out -> x, butterfly each step
  for (int t = T; t < OT; ++t) {
    const unsigned xu =
        (unsigned)__builtin_bit_cast(unsigned short, (_Float16)out_prev);
    cell(xu);
    float q = h * fcw;
#pragma unroll
    for (int off = 32; off > 0; off >>= 1) q += __shfl_xor(q, off, 64);
    const float out_t = q + fcb;
    obuf = (k == (t & 63)) ? out_t : obuf;
    if ((t & 63) == 63)
      out[(long)row * OT + (t - 63) + k] = obuf;           // coalesced
    out_prev = out_t;
  }
}

extern "C" void kernel_launch(void* const* d_in, const int* in_sizes, int n_in,
                              void* d_out, int out_size, void* d_ws, size_t ws_size,
                              hipStream_t stream) {
  const float* x    = (const float*)d_in[0];
  const float* W_ih = (const float*)d_in[1];
  const float* W_hh = (const float*)d_in[2];
  const float* b_ih = (const float*)d_in[3];
  const float* b_hh = (const float*)d_in[4];
  const float* fc_w = (const float*)d_in[5];
  const float* fc_b = (const float*)d_in[6];
  float* out = (float*)d_out;

  const int B  = 2048;
  const int T  = in_sizes[0] / B;   // 2048
  const int OT = out_size / B;      // 2176

  lstm_kernel<<<dim3(B), dim3(64), 0, stream>>>(x, W_ih, W_hh, b_ih, b_hh,
                                                fc_w, fc_b, out, T, OT);
}